// Round 1
// baseline (13.072 us; speedup 1.0000x reference)
//
#include <hip/hip_runtime.h>
#include <math.h>

// Problem constants (from setup_inputs): x [B,N,D], y [B,D,N], alt unused.
#define BN 4096   // N
#define BB 8      // B
#define NBLK 128  // grid for partial kernel
#define TB 256    // threads per block

// Kernel 1: one thread per (b, n) pair. Computes w(n) * ||x[b,n,:] - y[b,:,n]||
// and block-reduces to partial[blockIdx.x].
__global__ __launch_bounds__(TB) void diag_partial(
    const float* __restrict__ x,   // [B, N, 3]
    const float* __restrict__ y,   // [B, 3, N]
    float* __restrict__ partial)   // [NBLK]
{
    int tid = blockIdx.x * TB + threadIdx.x;   // 0 .. B*N-1 exactly
    int n = tid & (BN - 1);
    int b = tid >> 12;                          // tid / 4096

    const float* xp = x + ((size_t)b * BN + n) * 3;
    float x0 = xp[0], x1 = xp[1], x2 = xp[2];

    const float* yp = y + (size_t)b * 3 * BN + n;
    float y0 = yp[0], y1 = yp[BN], y2 = yp[2 * BN];

    float d0 = x0 - y0, d1 = x1 - y1, d2 = x2 - y2;
    float s = sqrtf(d0 * d0 + d1 * d1 + d2 * d2);
    if (n == 1 || n == 2) s *= 1.5f;   // diag[1:3] *= 1.5

    // wave (64-lane) reduction
    #pragma unroll
    for (int off = 32; off > 0; off >>= 1)
        s += __shfl_down(s, off, 64);

    __shared__ float lds[TB / 64];
    int lane = threadIdx.x & 63;
    int wid  = threadIdx.x >> 6;
    if (lane == 0) lds[wid] = s;
    __syncthreads();

    if (threadIdx.x == 0) {
        float t = 0.0f;
        #pragma unroll
        for (int i = 0; i < TB / 64; ++i) t += lds[i];
        partial[blockIdx.x] = t;
    }
}

// Kernel 2: deterministic final reduction of NBLK partials -> scalar mean.
__global__ __launch_bounds__(NBLK) void finalize(
    const float* __restrict__ partial,
    float* __restrict__ out)
{
    float s = partial[threadIdx.x];   // NBLK == 128 threads

    #pragma unroll
    for (int off = 32; off > 0; off >>= 1)
        s += __shfl_down(s, off, 64);

    __shared__ float lds[2];
    int lane = threadIdx.x & 63;
    int wid  = threadIdx.x >> 6;
    if (lane == 0) lds[wid] = s;
    __syncthreads();

    if (threadIdx.x == 0)
        out[0] = (lds[0] + lds[1]) * (1.0f / ((float)BB * (float)BN));
}

extern "C" void kernel_launch(void* const* d_in, const int* in_sizes, int n_in,
                              void* d_out, int out_size, void* d_ws, size_t ws_size,
                              hipStream_t stream) {
    const float* x = (const float*)d_in[0];   // [8, 4096, 3]
    const float* y = (const float*)d_in[1];   // [8, 3, 4096]
    // d_in[2] (alt) is dead code in the reference.

    float* partial = (float*)d_ws;            // NBLK floats of scratch
    float* out     = (float*)d_out;           // 1 float

    diag_partial<<<NBLK, TB, 0, stream>>>(x, y, partial);
    finalize<<<1, NBLK, 0, stream>>>(partial, out);
}